// Round 1
// baseline (326.228 us; speedup 1.0000x reference)
//
#include <hip/hip_runtime.h>
#include <math.h>

#define NB   8
#define NK   64
#define NL   1024
#define NCP  32
#define NAP  8
#define NG2  9
#define NCSA 16
#define NASA 16
#define NG3  3
#define NOC  256      // = NCP*NAP = NCSA*NASA
#define EPSQ 1e-8f
#define LT   16       // l-positions per block in kernel 1

// ---------------- Kernel 1: conv1 (k=9, SAME) + bias + squash(ap=8) ----------
// grid = NB * (NL/LT) = 512 blocks, 256 threads (thread = output channel oc)
__global__ __launch_bounds__(256) void k1_conv1_squash(
    const float* __restrict__ x, const float* __restrict__ w1,
    const float* __restrict__ b1, float* __restrict__ ysq)
{
    __shared__ alignas(16) float xs[NK][LT + NG2 - 1];   // [64][24] = 6 KB
    const int tid = threadIdx.x;
    const int bid = blockIdx.x;
    const int b   = bid >> 6;            // 64 = NL/LT
    const int l0  = (bid & 63) * LT;

    const float* xb = x + (size_t)b * NK * NL;
    for (int i = tid; i < NK * (LT + 8); i += 256) {
        int row = i / 24, col = i - row * 24;
        int l = l0 + col - 4;
        xs[row][col] = (l >= 0 && l < NL) ? xb[row * NL + l] : 0.0f;
    }

    float acc[LT];
    {
        float bb = b1[tid];
#pragma unroll
        for (int i = 0; i < LT; ++i) acc[i] = bb;
    }
    __syncthreads();

    const float* wrow = w1 + (size_t)tid * (NK * NG2);   // this oc's weights
    for (int k = 0; k < NK; ++k) {
        float wk[NG2];
#pragma unroll
        for (int g = 0; g < NG2; ++g) wk[g] = wrow[k * NG2 + g];
        // broadcast LDS row -> regs (uniform address across wave)
        float xr[LT + NG2 - 1];
        const float4* xrow4 = (const float4*)(&xs[k][0]);
#pragma unroll
        for (int q = 0; q < 6; ++q) {
            float4 v = xrow4[q];
            xr[q*4+0] = v.x; xr[q*4+1] = v.y; xr[q*4+2] = v.z; xr[q*4+3] = v.w;
        }
#pragma unroll
        for (int l = 0; l < LT; ++l)
#pragma unroll
            for (int g = 0; g < NG2; ++g)
                acc[l] = fmaf(xr[l + g], wk[g], acc[l]);
    }

    // squash over ap = groups of 8 consecutive lanes (oc = cp*8+ap)
    float* yb = ysq + ((size_t)b * NL + l0) * NOC + tid;
#pragma unroll
    for (int l = 0; l < LT; ++l) {
        float sq = acc[l] * acc[l];
        sq += __shfl_xor(sq, 1);
        sq += __shfl_xor(sq, 2);
        sq += __shfl_xor(sq, 4);
        float val = sq / (1.0f + sq) * acc[l] / sqrtf(sq + EPSQ);
        yb[(size_t)l * NOC] = val;     // coalesced: 256 lanes -> 256 consecutive
    }
}

// ---------------- Kernel 2: conv2 (3x8 stride 8) + dynamic routing (3 iters) --
// grid = NB*NL = 8192 blocks (one (b,l) site), 256 threads
__global__ __launch_bounds__(256) void k2_conv2_routing(
    const float* __restrict__ ysq, const float* __restrict__ w2,
    const float* __restrict__ b2, float* __restrict__ out)
{
    __shared__ float VT[NOC][NCP + 1];            // V transposed [oc][cp], pad 33 -> 33.8 KB
    __shared__ alignas(16) float yp[NG3][NOC];    // y patch rows l-1..l+1, 3 KB
    __shared__ float br[NCP][NCSA + 1];           // routing logits
    __shared__ float cc[NCP][NCSA + 1];           // softmax coeffs
    __shared__ float vv[NCSA][NASA + 1];          // squashed v

    const int tid = threadIdx.x;
    const int bid = blockIdx.x;
    const int b = bid >> 10;
    const int l = bid & (NL - 1);

    // stage y patch (zero-pad rows outside [0,L))
#pragma unroll
    for (int g = 0; g < NG3; ++g) {
        int row = l + g - 1;
        yp[g][tid] = (row >= 0 && row < NL) ? ysq[((size_t)b * NL + row) * NOC + tid] : 0.0f;
    }
    // zero routing logits (512 entries)
    br[tid >> 4][tid & 15] = 0.0f;
    br[(tid + 256) >> 4][tid & 15] = 0.0f;
    __syncthreads();

    // ---- V compute: thread owns cp in {cpg+8i} (4), oc = ocg+32j (8) ----
    const int ocg = tid & 31;
    const int cpg = tid >> 5;
    float yr[4][24];
#pragma unroll
    for (int ci = 0; ci < 4; ++ci) {
        int cp = cpg + 8 * ci;
#pragma unroll
        for (int g = 0; g < 3; ++g) {
            const float4* p = (const float4*)(&yp[g][cp * 8]);
            float4 v0 = p[0], v1 = p[1];
            yr[ci][g*8+0]=v0.x; yr[ci][g*8+1]=v0.y; yr[ci][g*8+2]=v0.z; yr[ci][g*8+3]=v0.w;
            yr[ci][g*8+4]=v1.x; yr[ci][g*8+5]=v1.y; yr[ci][g*8+6]=v1.z; yr[ci][g*8+7]=v1.w;
        }
    }
#pragma unroll 2
    for (int j = 0; j < 8; ++j) {
        int oc = ocg + 32 * j;
        const float4* wp4 = (const float4*)(w2 + oc * 24);   // 96B-aligned
        float wk[24];
#pragma unroll
        for (int q = 0; q < 6; ++q) {
            float4 v = wp4[q];
            wk[q*4+0]=v.x; wk[q*4+1]=v.y; wk[q*4+2]=v.z; wk[q*4+3]=v.w;
        }
        float bias = b2[oc];
        float a0 = bias, a1 = bias, a2 = bias, a3 = bias;
#pragma unroll
        for (int i = 0; i < 24; ++i) {
            a0 = fmaf(yr[0][i], wk[i], a0);
            a1 = fmaf(yr[1][i], wk[i], a1);
            a2 = fmaf(yr[2][i], wk[i], a2);
            a3 = fmaf(yr[3][i], wk[i], a3);
        }
        VT[oc][cpg]      = a0;
        VT[oc][cpg + 8]  = a1;
        VT[oc][cpg + 16] = a2;
        VT[oc][cpg + 24] = a3;
    }
    __syncthreads();

    // ---- routing: 3 iterations ----
    const int cp_s = tid >> 3, cs = tid & 7;     // softmax/a-step mapping
    const int csa  = tid >> 4, asa = tid & 15;   // s-step mapping (tid == oc)
    for (int r = 0; r < 3; ++r) {
        // softmax over csa (16 values spread over 8 consecutive lanes x 2 regs)
        float t0 = br[cp_s][cs], t1 = br[cp_s][cs + 8];
        float m = fmaxf(t0, t1);
        m = fmaxf(m, __shfl_xor(m, 1));
        m = fmaxf(m, __shfl_xor(m, 2));
        m = fmaxf(m, __shfl_xor(m, 4));
        float e0 = __expf(t0 - m), e1 = __expf(t1 - m);
        float ssum = e0 + e1;
        ssum += __shfl_xor(ssum, 1);
        ssum += __shfl_xor(ssum, 2);
        ssum += __shfl_xor(ssum, 4);
        float inv = 1.0f / ssum;
        cc[cp_s][cs]     = e0 * inv;
        cc[cp_s][cs + 8] = e1 * inv;
        __syncthreads();

        // s[csa][asa] = sum_cp c[cp][csa] * V[cp][csa][asa]; thread = oc = tid
        float sv = 0.0f;
#pragma unroll 8
        for (int cp = 0; cp < NCP; ++cp)
            sv = fmaf(cc[cp][csa], VT[tid][cp], sv);
        // squash over asa = 16 consecutive lanes
        float sq = sv * sv;
        sq += __shfl_xor(sq, 1);
        sq += __shfl_xor(sq, 2);
        sq += __shfl_xor(sq, 4);
        sq += __shfl_xor(sq, 8);
        float vval = sq / (1.0f + sq) * sv / sqrtf(sq + EPSQ);

        if (r == 2) {
            out[((size_t)b * NL + l) * NOC + tid] = vval;   // coalesced
        } else {
            vv[csa][asa] = vval;
            __syncthreads();
            // a[cp][csa] = sum_asa V[cp][csa][asa]*v[csa][asa]; 2 pairs/thread
            float a0 = 0.0f, a1 = 0.0f;
#pragma unroll
            for (int q = 0; q < NASA; ++q) {
                a0 = fmaf(VT[cs * 16 + q][cp_s],       vv[cs][q],     a0);
                a1 = fmaf(VT[(cs + 8) * 16 + q][cp_s], vv[cs + 8][q], a1);
            }
            br[cp_s][cs]     += a0;
            br[cp_s][cs + 8] += a1;
            __syncthreads();
        }
    }
}

extern "C" void kernel_launch(void* const* d_in, const int* in_sizes, int n_in,
                              void* d_out, int out_size, void* d_ws, size_t ws_size,
                              hipStream_t stream)
{
    const float* x  = (const float*)d_in[0];
    const float* w1 = (const float*)d_in[1];
    const float* b1 = (const float*)d_in[2];
    const float* w2 = (const float*)d_in[3];
    const float* b2 = (const float*)d_in[4];
    float* outp = (float*)d_out;
    float* ysq  = (float*)d_ws;            // needs 8*1024*256*4 = 8 MB scratch

    k1_conv1_squash<<<NB * (NL / LT), 256, 0, stream>>>(x, w1, b1, ysq);
    k2_conv2_routing<<<NB * NL, 256, 0, stream>>>(ysq, w2, b2, outp);
}

// Round 2
// 200.200 us; speedup vs baseline: 1.6295x; 1.6295x over previous
//
#include <hip/hip_runtime.h>
#include <math.h>

#define NB   8
#define NK   64
#define NL   1024
#define NCP  32
#define NAP  8
#define NG2  9
#define NCSA 16
#define NASA 16
#define NG3  3
#define NOC  256      // = NCP*NAP = NCSA*NASA
#define EPSQ 1e-8f
#define LT   8        // l-positions per block in kernel 1

// ---------------- Kernel 1: conv1 (k=9, SAME) + bias + squash(ap=8) ----------
// grid = NB * (NL/LT) = 1024 blocks, 256 threads (thread = output channel oc)
__global__ __launch_bounds__(256, 4) void k1_conv1_squash(
    const float* __restrict__ x, const float* __restrict__ w1,
    const float* __restrict__ b1, float* __restrict__ ysq)
{
    __shared__ alignas(16) float xs[NK][LT + NG2 - 1];   // [64][16] = 4 KB
    const int tid = threadIdx.x;
    const int bid = blockIdx.x;
    const int b   = bid >> 7;            // 128 = NL/LT
    const int l0  = (bid & 127) * LT;

    const float* xb = x + (size_t)b * NK * NL;
    for (int i = tid; i < NK * (LT + 8); i += 256) {
        int row = i >> 4, col = i & 15;
        int l = l0 + col - 4;
        xs[row][col] = (l >= 0 && l < NL) ? xb[row * NL + l] : 0.0f;
    }

    float acc[LT];
    {
        float bb = b1[tid];
#pragma unroll
        for (int i = 0; i < LT; ++i) acc[i] = bb;
    }
    __syncthreads();

    const float* wrow = w1 + (size_t)tid * (NK * NG2);   // this oc's weights
    // process k in groups of 4: 36 floats = 9 float4 (16B-aligned at k%4==0)
    for (int k4 = 0; k4 < NK; k4 += 4) {
        float wk[36];
        const float4* wp4 = (const float4*)(wrow + k4 * NG2);
#pragma unroll
        for (int q = 0; q < 9; ++q) {
            float4 v = wp4[q];
            wk[q*4+0]=v.x; wk[q*4+1]=v.y; wk[q*4+2]=v.z; wk[q*4+3]=v.w;
        }
#pragma unroll
        for (int kk = 0; kk < 4; ++kk) {
            float xr[LT + NG2 - 1];
            const float4* xrow4 = (const float4*)(&xs[k4 + kk][0]);
#pragma unroll
            for (int q = 0; q < 4; ++q) {
                float4 v = xrow4[q];
                xr[q*4+0] = v.x; xr[q*4+1] = v.y; xr[q*4+2] = v.z; xr[q*4+3] = v.w;
            }
#pragma unroll
            for (int l = 0; l < LT; ++l)
#pragma unroll
                for (int g = 0; g < NG2; ++g)
                    acc[l] = fmaf(xr[l + g], wk[kk * NG2 + g], acc[l]);
        }
    }

    // squash over ap = groups of 8 consecutive lanes (oc = cp*8+ap)
    float* yb = ysq + ((size_t)b * NL + l0) * NOC + tid;
#pragma unroll
    for (int l = 0; l < LT; ++l) {
        float sq = acc[l] * acc[l];
        sq += __shfl_xor(sq, 1);
        sq += __shfl_xor(sq, 2);
        sq += __shfl_xor(sq, 4);
        float val = sq / (1.0f + sq) * acc[l] / sqrtf(sq + EPSQ);
        yb[(size_t)l * NOC] = val;     // coalesced
    }
}

// ---------------- Kernel 2: conv2 (3x8 stride 8) + dynamic routing (3 iters) --
// grid = NB*NL = 8192 blocks (one (b,l) site), 256 threads
struct RoutBufs {
    float br[NCP][NCSA + 1];   // routing logits
    float cc[NCP][NCSA + 1];   // softmax coeffs
    float vv[NCSA][NASA + 1];  // squashed v
};
union ShmU {
    float yp[NG3][NOC];        // y patch (dead after V-compute)
    RoutBufs r;                // routing buffers (live after V-compute)
};

__global__ __launch_bounds__(256, 4) void k2_conv2_routing(
    const float* __restrict__ ysq, const float* __restrict__ w2,
    const float* __restrict__ b2, float* __restrict__ out)
{
    __shared__ float VT[NOC][NCP + 1];   // V transposed [oc][cp], pad 33: 33.8 KB
    __shared__ ShmU u;                   // 5.4 KB  -> total 38.3 KB

    const int tid = threadIdx.x;
    const int bid = blockIdx.x;
    const int b = bid >> 10;
    const int l = bid & (NL - 1);

    // stage y patch (zero-pad rows outside [0,L))
#pragma unroll
    for (int g = 0; g < NG3; ++g) {
        int row = l + g - 1;
        u.yp[g][tid] = (row >= 0 && row < NL) ? ysq[((size_t)b * NL + row) * NOC + tid] : 0.0f;
    }
    __syncthreads();

    // ---- V compute: thread owns cp in {cpg+8i} (4), oc = ocg+32j (8) ----
    const int ocg = tid & 31;
    const int cpg = tid >> 5;
    float yr[4][24];
#pragma unroll
    for (int ci = 0; ci < 4; ++ci) {
        int cp = cpg + 8 * ci;
#pragma unroll
        for (int g = 0; g < 3; ++g) {
            const float4* p = (const float4*)(&u.yp[g][cp * 8]);
            float4 v0 = p[0], v1 = p[1];
            yr[ci][g*8+0]=v0.x; yr[ci][g*8+1]=v0.y; yr[ci][g*8+2]=v0.z; yr[ci][g*8+3]=v0.w;
            yr[ci][g*8+4]=v1.x; yr[ci][g*8+5]=v1.y; yr[ci][g*8+6]=v1.z; yr[ci][g*8+7]=v1.w;
        }
    }
    for (int j = 0; j < 8; ++j) {
        int oc = ocg + 32 * j;
        const float4* wp4 = (const float4*)(w2 + oc * 24);   // 96B-aligned
        float bias = b2[oc];
        float a0 = bias, a1 = bias, a2 = bias, a3 = bias;
#pragma unroll
        for (int q = 0; q < 6; ++q) {
            float4 w = wp4[q];
            a0 = fmaf(yr[0][q*4+0], w.x, a0); a0 = fmaf(yr[0][q*4+1], w.y, a0);
            a0 = fmaf(yr[0][q*4+2], w.z, a0); a0 = fmaf(yr[0][q*4+3], w.w, a0);
            a1 = fmaf(yr[1][q*4+0], w.x, a1); a1 = fmaf(yr[1][q*4+1], w.y, a1);
            a1 = fmaf(yr[1][q*4+2], w.z, a1); a1 = fmaf(yr[1][q*4+3], w.w, a1);
            a2 = fmaf(yr[2][q*4+0], w.x, a2); a2 = fmaf(yr[2][q*4+1], w.y, a2);
            a2 = fmaf(yr[2][q*4+2], w.z, a2); a2 = fmaf(yr[2][q*4+3], w.w, a2);
            a3 = fmaf(yr[3][q*4+0], w.x, a3); a3 = fmaf(yr[3][q*4+1], w.y, a3);
            a3 = fmaf(yr[3][q*4+2], w.z, a3); a3 = fmaf(yr[3][q*4+3], w.w, a3);
        }
        VT[oc][cpg]      = a0;
        VT[oc][cpg + 8]  = a1;
        VT[oc][cpg + 16] = a2;
        VT[oc][cpg + 24] = a3;
    }
    __syncthreads();

    // ---- routing ----
    const int cp_s = tid >> 3, cs = tid & 7;     // softmax/a-step mapping
    const int csa  = tid >> 4, asa = tid & 15;   // s-step mapping (tid == oc)

    // own VT row is iteration-invariant: hoist to registers (V-compute regs dead)
    float Vreg[NCP];
#pragma unroll
    for (int cp = 0; cp < NCP; ++cp) Vreg[cp] = VT[tid][cp];

    // ---- r = 0: b == 0 -> softmax is uniform 1/16
    {
        float sv = 0.0f;
#pragma unroll
        for (int cp = 0; cp < NCP; ++cp) sv += Vreg[cp];
        sv *= 0.0625f;
        float sq = sv * sv;
        sq += __shfl_xor(sq, 1);
        sq += __shfl_xor(sq, 2);
        sq += __shfl_xor(sq, 4);
        sq += __shfl_xor(sq, 8);
        float vval = sq / (1.0f + sq) * sv / sqrtf(sq + EPSQ);
        u.r.vv[csa][asa] = vval;
        __syncthreads();
        float a0 = 0.0f, a1 = 0.0f;
#pragma unroll
        for (int q = 0; q < NASA; ++q) {
            a0 = fmaf(VT[cs * 16 + q][cp_s],       u.r.vv[cs][q],     a0);
            a1 = fmaf(VT[(cs + 8) * 16 + q][cp_s], u.r.vv[cs + 8][q], a1);
        }
        u.r.br[cp_s][cs]     = a0;   // b was 0: assign
        u.r.br[cp_s][cs + 8] = a1;
        __syncthreads();
    }

    // ---- r = 1, 2
    for (int r = 1; r < 3; ++r) {
        float t0 = u.r.br[cp_s][cs], t1 = u.r.br[cp_s][cs + 8];
        float m = fmaxf(t0, t1);
        m = fmaxf(m, __shfl_xor(m, 1));
        m = fmaxf(m, __shfl_xor(m, 2));
        m = fmaxf(m, __shfl_xor(m, 4));
        float e0 = __expf(t0 - m), e1 = __expf(t1 - m);
        float ssum = e0 + e1;
        ssum += __shfl_xor(ssum, 1);
        ssum += __shfl_xor(ssum, 2);
        ssum += __shfl_xor(ssum, 4);
        float inv = 1.0f / ssum;
        u.r.cc[cp_s][cs]     = e0 * inv;
        u.r.cc[cp_s][cs + 8] = e1 * inv;
        __syncthreads();

        float sv = 0.0f;
#pragma unroll
        for (int cp = 0; cp < NCP; ++cp)
            sv = fmaf(u.r.cc[cp][csa], Vreg[cp], sv);
        float sq = sv * sv;
        sq += __shfl_xor(sq, 1);
        sq += __shfl_xor(sq, 2);
        sq += __shfl_xor(sq, 4);
        sq += __shfl_xor(sq, 8);
        float vval = sq / (1.0f + sq) * sv / sqrtf(sq + EPSQ);

        if (r == 2) {
            out[((size_t)b * NL + l) * NOC + tid] = vval;   // coalesced
        } else {
            u.r.vv[csa][asa] = vval;
            __syncthreads();
            float a0 = 0.0f, a1 = 0.0f;
#pragma unroll
            for (int q = 0; q < NASA; ++q) {
                a0 = fmaf(VT[cs * 16 + q][cp_s],       u.r.vv[cs][q],     a0);
                a1 = fmaf(VT[(cs + 8) * 16 + q][cp_s], u.r.vv[cs + 8][q], a1);
            }
            u.r.br[cp_s][cs]     += a0;
            u.r.br[cp_s][cs + 8] += a1;
            __syncthreads();
        }
    }
}

extern "C" void kernel_launch(void* const* d_in, const int* in_sizes, int n_in,
                              void* d_out, int out_size, void* d_ws, size_t ws_size,
                              hipStream_t stream)
{
    const float* x  = (const float*)d_in[0];
    const float* w1 = (const float*)d_in[1];
    const float* b1 = (const float*)d_in[2];
    const float* w2 = (const float*)d_in[3];
    const float* b2 = (const float*)d_in[4];
    float* outp = (float*)d_out;
    float* ysq  = (float*)d_ws;            // 8*1024*256*4 = 8 MB scratch

    k1_conv1_squash<<<NB * (NL / LT), 256, 0, stream>>>(x, w1, b1, ysq);
    k2_conv2_routing<<<NB * NL, 256, 0, stream>>>(ysq, w2, b2, outp);
}